// Round 4
// baseline (593.321 us; speedup 1.0000x reference)
//
#include <hip/hip_runtime.h>
#include <hip/hip_bf16.h>

// out[b,s,h] = sum_d x[b,s,d] * W[cat[b],d,h] + bias[cat[b],h]
// Strategy: prepass casts x -> bf16 [B][S][K], W -> bf16 transposed [C][N][K]
// in d_ws; then 256x256 8-phase bf16 GEMM (T2 swizzle + T3/T4 counted vmcnt +
// T5 setprio + T1 XCD swizzle). Fallback (ws too small): R1-style fused kernel.

#define SEQ 512
#define DIN 1024
#define DH  4096
#define NCAT 16
#define NB   64

#define BM 256
#define BN 256
#define BK 64
#define NT 512
#define NTILES (DIN / BK)

typedef __attribute__((ext_vector_type(8))) short   short8;
typedef __attribute__((ext_vector_type(8))) __bf16  bf16x8;
typedef __attribute__((ext_vector_type(4))) __bf16  bf16x4;
typedef __attribute__((ext_vector_type(4))) float   f32x4;

static __device__ __forceinline__ void gload_lds16(const void* g, void* l) {
    __builtin_amdgcn_global_load_lds(
        (const __attribute__((address_space(1))) void*)g,
        (__attribute__((address_space(3))) void*)l,
        16, 0, 0);
}

static __device__ __forceinline__ void bar() {
    asm volatile("" ::: "memory");
    __builtin_amdgcn_s_barrier();
    asm volatile("" ::: "memory");
}

#define MFMA_BF16(a, b, c) __builtin_amdgcn_mfma_f32_16x16x32_bf16((a), (b), (c), 0, 0, 0)

// ---------------- prepass 1: x f32 -> bf16 ----------------
__global__ __launch_bounds__(256)
void conv_x(const float* __restrict__ x, __bf16* __restrict__ xb, int n8) {
    int idx = blockIdx.x * 256 + threadIdx.x;
    const int stride = gridDim.x * 256;
    for (; idx < n8; idx += stride) {
        const f32x4 a = ((const f32x4*)x)[(size_t)idx * 2];
        const f32x4 b = ((const f32x4*)x)[(size_t)idx * 2 + 1];
        bf16x8 h;
        h[0]=(__bf16)a[0]; h[1]=(__bf16)a[1]; h[2]=(__bf16)a[2]; h[3]=(__bf16)a[3];
        h[4]=(__bf16)b[0]; h[5]=(__bf16)b[1]; h[6]=(__bf16)b[2]; h[7]=(__bf16)b[3];
        ((bf16x8*)xb)[idx] = h;
    }
}

// ------- prepass 2: W [C][K][N] f32 -> Wt [C][N][K] bf16 (LDS transpose) -------
__global__ __launch_bounds__(256)
void conv_w(const float* __restrict__ W, __bf16* __restrict__ wt) {
    __shared__ float lt[64][65];
    const int t  = threadIdx.x;
    const int nb = blockIdx.x * 64;
    const int kb = blockIdx.y * 64;
    const int c  = blockIdx.z;
    #pragma unroll
    for (int p = 0; p < 4; p++) {
        const int row = (t >> 4) + p * 16;
        const int col = (t & 15) * 4;
        const f32x4 v = *(const f32x4*)(W + ((size_t)c * DIN + kb + row) * DH + nb + col);
        lt[row][col] = v[0]; lt[row][col+1] = v[1];
        lt[row][col+2] = v[2]; lt[row][col+3] = v[3];
    }
    __syncthreads();
    #pragma unroll
    for (int p = 0; p < 2; p++) {
        const int n  = (t >> 3) + p * 32;
        const int k0 = (t & 7) * 8;
        bf16x8 h;
        #pragma unroll
        for (int j = 0; j < 8; j++) h[j] = (__bf16)lt[k0 + j][n];
        *(bf16x8*)(wt + ((size_t)c * DH + nb + n) * DIN + kb + k0) = h;
    }
}

// ------------- main GEMM: 256x256, BK=64, 8 waves, 4-phase/K-tile -------------
// LDS slot (row, g) holds element columns (g ^ (row&7))*8.. : staged via
// inverse-permuted global source, read with same XOR (0 conflicts, verified R3).
// Pipeline: double-buffered half-tile slots; stage of tile j+1 issued across
// the 4 phases of tile j; single counted vmcnt(2) per K-tile (never drain-0).

#define READQ(Q)                                                         \
    const short8 aq##Q##00 = rdfrag(As, (2*(Q)    )*16 + l15, 0);        \
    const short8 aq##Q##01 = rdfrag(As, (2*(Q)    )*16 + l15, 1);        \
    const short8 aq##Q##10 = rdfrag(As, (2*(Q) + 1)*16 + l15, 0);        \
    const short8 aq##Q##11 = rdfrag(As, (2*(Q) + 1)*16 + l15, 1);

#define MMAQ(Q)                                                                   \
    __builtin_amdgcn_s_setprio(1);                                                \
    _Pragma("unroll")                                                             \
    for (int fn = 0; fn < 4; fn++) {                                              \
        acc[2*(Q)][fn]     = MFMA_BF16(aq##Q##00, bq[fn][0], acc[2*(Q)][fn]);     \
        acc[2*(Q)][fn]     = MFMA_BF16(aq##Q##01, bq[fn][1], acc[2*(Q)][fn]);     \
        acc[2*(Q) + 1][fn] = MFMA_BF16(aq##Q##10, bq[fn][0], acc[2*(Q) + 1][fn]); \
        acc[2*(Q) + 1][fn] = MFMA_BF16(aq##Q##11, bq[fn][1], acc[2*(Q) + 1][fn]); \
    }                                                                             \
    __builtin_amdgcn_s_setprio(0);

__global__ __launch_bounds__(NT, 2)
void gemm_bt8(const __bf16* __restrict__ xb, const int* __restrict__ cat_ids,
              const __bf16* __restrict__ wt, const float* __restrict__ bias,
              float* __restrict__ out) {
    __shared__ __align__(16) __bf16 lA[2][2][128 * 64];   // [buf][half] 64 KB
    __shared__ __align__(16) __bf16 lB[2][2][128 * 64];   // 64 KB

    const int t    = threadIdx.x;
    const int lane = t & 63;
    const int w    = t >> 6;
    const int wm   = (w >> 2) * 128;     // 2 m-waves
    const int wn   = (w & 3) * 64;       // 4 n-waves
    const int l15  = lane & 15;
    const int lg   = lane >> 4;

    // T1: bijective XCD swizzle (gridDim.x % 8 == 0)
    const unsigned o = blockIdx.x;
    const unsigned s = (o & 7) * (gridDim.x >> 3) + (o >> 3);
    const int bb = s >> 5;
    const int nb = ((s >> 1) & 15) * BN;
    const int mb = (s & 1) * BM;
    const int c  = cat_ids[bb];

    const __bf16* xp = xb + ((size_t)bb * SEQ + mb) * DIN;
    const __bf16* wp = wt + ((size_t)c * DH + nb) * DIN;

    // staging: 2 chunks/thread/half-tile; chunk ch: row=ch>>3, grp=ch&7,
    // source grp' = grp ^ (row&7)  (inverse swizzle on the GLOBAL side)
    int srow[2], scol[2], sdst[2];
    #pragma unroll
    for (int L = 0; L < 2; L++) {
        const int ch = L * NT + t;
        srow[L] = ch >> 3;
        scol[L] = ((ch & 7) ^ ((ch >> 3) & 7)) * 8;
        sdst[L] = ch * 8;
    }
    auto stageA = [&](int buf, int half, int kt) {
        #pragma unroll
        for (int L = 0; L < 2; L++)
            gload_lds16(xp + (size_t)(half * 128 + srow[L]) * DIN + kt + scol[L],
                        &lA[buf][half][sdst[L]]);
    };
    auto stageB = [&](int buf, int half, int kt) {
        #pragma unroll
        for (int L = 0; L < 2; L++)
            gload_lds16(wp + (size_t)(half * 128 + srow[L]) * DIN + kt + scol[L],
                        &lB[buf][half][sdst[L]]);
    };
    auto rdfrag = [&](const __bf16* slot, int row, int ks) -> short8 {
        const int off = row * 128 + ((ks * 64 + lg * 16) ^ ((row & 7) << 4));
        return *(const short8*)((const char*)slot + off);
    };

    f32x4 acc[8][4];
    #pragma unroll
    for (int i = 0; i < 8; i++)
        #pragma unroll
        for (int j = 0; j < 4; j++) acc[i][j] = (f32x4)0.f;
    short8 bq[4][2];

    // prologue: stage all of tile 0 into buf 0 (8 loads in flight)
    stageA(0, 0, 0); stageA(0, 1, 0);
    stageB(0, 0, 0); stageB(0, 1, 0);

    for (int j = 0; j < NTILES; ++j) {
        const int cur = j & 1;
        const int nxt = cur ^ 1;
        const int ktn = (j + 1) * BK;
        const bool pf = (j + 1 < NTILES);
        const __bf16* As = &lA[cur][wm >> 7][0];
        const __bf16* Bs = &lB[cur][wn >> 7][0];

        // ---- phase 0: issue next A-half0, counted wait, B-frags + quad 0 ----
        if (pf) {
            stageA(nxt, 0, ktn);
            asm volatile("s_waitcnt vmcnt(2)" ::: "memory");  // tile j landed
        } else {
            asm volatile("s_waitcnt vmcnt(0)" ::: "memory");
        }
        bar();
        #pragma unroll
        for (int fn = 0; fn < 4; fn++)
            #pragma unroll
            for (int ks = 0; ks < 2; ks++)
                bq[fn][ks] = rdfrag(Bs, (wn & 64) + fn * 16 + l15, ks);
        READQ(0)
        MMAQ(0)
        bar();
        // ---- phase 1 ----
        READQ(1)
        if (pf) stageA(nxt, 1, ktn);
        bar();
        MMAQ(1)
        bar();
        // ---- phase 2 ----
        READQ(2)
        if (pf) stageB(nxt, 0, ktn);
        bar();
        MMAQ(2)
        bar();
        // ---- phase 3 ----
        READQ(3)
        if (pf) stageB(nxt, 1, ktn);
        bar();
        MMAQ(3)
        bar();
    }

    // epilogue: D[row = lg*4 + r][col = l15] per 16x16 frag (verified R1/R3)
    const float* bp = bias + (size_t)c * DH;
    float*       op = out + (size_t)bb * SEQ * DH;
    #pragma unroll
    for (int fn = 0; fn < 4; fn++) {
        const int col = nb + wn + fn * 16 + l15;
        const float bv = bp[col];
        #pragma unroll
        for (int fm = 0; fm < 8; fm++) {
            const int row0 = mb + wm + fm * 16 + lg * 4;
            #pragma unroll
            for (int r = 0; r < 4; r++)
                op[(size_t)(row0 + r) * DH + col] = acc[fm][fn][r] + bv;
        }
    }
}

// ---------------- fallback (ws too small): fused 128x128 ----------------
static __device__ __forceinline__ int swz_fb(int row) {
    return ((row ^ (row >> 3)) & 7) << 4;
}
__global__ __launch_bounds__(256, 2)
void cat_lin_fb(const float* __restrict__ x, const int* __restrict__ cat_ids,
                const float* __restrict__ W, const float* __restrict__ bias,
                float* __restrict__ out) {
    __shared__ unsigned char lAf[128 * 64 * 2];
    __shared__ unsigned char lBf[128 * 64 * 2];
    const int t = threadIdx.x, lane = t & 63, wave = t >> 6;
    const int wm = (wave >> 1) * 64, wn = (wave & 1) * 64;
    const int l15 = lane & 15, lg = lane >> 4;
    const int nb = blockIdx.x * 128, mb = blockIdx.y * 128, bb = blockIdx.z;
    const int c = cat_ids[bb];
    const float* xp = x + (size_t)bb * SEQ * DIN + (size_t)mb * DIN;
    const float* wp = W + (size_t)c * DIN * DH + nb;
    f32x4 acc[4][4];
    #pragma unroll
    for (int i = 0; i < 4; i++)
        #pragma unroll
        for (int j = 0; j < 4; j++) acc[i][j] = (f32x4)0.f;
    const int aM = t >> 4, aK = (t & 15) * 4;
    const int bN = (t & 31) * 4, bK = (t >> 5) * 4;
    for (int kt = 0; kt < DIN; kt += 64) {
        #pragma unroll
        for (int i = 0; i < 8; i++) {
            const int m = aM + i * 16;
            const f32x4 v = *(const f32x4*)(xp + (size_t)m * DIN + kt + aK);
            bf16x4 h;
            h[0]=(__bf16)v[0]; h[1]=(__bf16)v[1]; h[2]=(__bf16)v[2]; h[3]=(__bf16)v[3];
            *(bf16x4*)(&lAf[m * 128 + ((aK * 2) ^ swz_fb(m))]) = h;
        }
        #pragma unroll
        for (int i = 0; i < 2; i++) {
            const int k0 = bK + i * 32;
            const float* wr = wp + (size_t)(kt + k0) * DH + bN;
            const f32x4 r0 = *(const f32x4*)(wr);
            const f32x4 r1 = *(const f32x4*)(wr + DH);
            const f32x4 r2 = *(const f32x4*)(wr + 2 * (size_t)DH);
            const f32x4 r3 = *(const f32x4*)(wr + 3 * (size_t)DH);
            #pragma unroll
            for (int jj = 0; jj < 4; jj++) {
                bf16x4 h;
                h[0]=(__bf16)r0[jj]; h[1]=(__bf16)r1[jj];
                h[2]=(__bf16)r2[jj]; h[3]=(__bf16)r3[jj];
                const int n = bN + jj;
                *(bf16x4*)(&lBf[n * 128 + ((k0 * 2) ^ swz_fb(n))]) = h;
            }
        }
        __syncthreads();
        #pragma unroll
        for (int ks = 0; ks < 2; ks++) {
            const int kb2 = ks * 64 + lg * 16;
            short8 bfv[4];
            #pragma unroll
            for (int fn = 0; fn < 4; fn++) {
                const int n = wn + fn * 16 + l15;
                bfv[fn] = *(const short8*)(&lBf[n * 128 + (kb2 ^ swz_fb(n))]);
            }
            #pragma unroll
            for (int fm = 0; fm < 4; fm++) {
                const int m = wm + fm * 16 + l15;
                const short8 af = *(const short8*)(&lAf[m * 128 + (kb2 ^ swz_fb(m))]);
                #pragma unroll
                for (int fn = 0; fn < 4; fn++)
                    acc[fm][fn] = MFMA_BF16(af, bfv[fn], acc[fm][fn]);
            }
        }
        __syncthreads();
    }
    const float* bp = bias + (size_t)c * DH;
    float* op = out + (size_t)bb * SEQ * DH;
    #pragma unroll
    for (int fn = 0; fn < 4; fn++) {
        const int col = nb + wn + fn * 16 + l15;
        const float bv = bp[col];
        #pragma unroll
        for (int fm = 0; fm < 4; fm++) {
            const int row0 = mb + wm + fm * 16 + lg * 4;
            #pragma unroll
            for (int r = 0; r < 4; r++)
                op[(size_t)(row0 + r) * DH + col] = acc[fm][fn][r] + bv;
        }
    }
}

extern "C" void kernel_launch(void* const* d_in, const int* in_sizes, int n_in,
                              void* d_out, int out_size, void* d_ws, size_t ws_size,
                              hipStream_t stream) {
    const float* x   = (const float*)d_in[0];
    const int*   cid = (const int*)d_in[1];
    const float* W   = (const float*)d_in[2];
    const float* b   = (const float*)d_in[3];
    float*       out = (float*)d_out;

    const size_t xb_bytes = (size_t)NB * SEQ * DIN * 2;
    const size_t wt_bytes = (size_t)NCAT * DH * DIN * 2;

    if (ws_size >= xb_bytes + wt_bytes) {
        __bf16* xbuf = (__bf16*)d_ws;
        __bf16* wbuf = (__bf16*)((char*)d_ws + xb_bytes);
        conv_x<<<2048, 256, 0, stream>>>(x, xbuf, NB * SEQ * DIN / 8);
        dim3 gw(DH / 64, DIN / 64, NCAT);
        conv_w<<<gw, 256, 0, stream>>>(W, wbuf);
        // 2048 blocks: 64 batches x (16 nb x 2 mb), flattened for XCD swizzle
        gemm_bt8<<<dim3(NB * (DH / BN) * (SEQ / BM)), dim3(NT), 0, stream>>>(
            xbuf, cid, wbuf, b, out);
    } else {
        dim3 gg(DH / 128, SEQ / 128, NB);
        cat_lin_fb<<<gg, 256, 0, stream>>>(x, cid, W, b, out);
    }
}

// Round 5
// 582.128 us; speedup vs baseline: 1.0192x; 1.0192x over previous
//
#include <hip/hip_runtime.h>
#include <hip/hip_bf16.h>

// out[b,s,h] = sum_d x[b,s,d] * W[cat[b],d,h] + bias[cat[b],h]
// Strategy: prepass casts x -> bf16 [B][S][K], W -> bf16 transposed [C][N][K]
// in d_ws; then 256x256 bf16 GEMM, 4 phases/K-tile, deep half-granular
// prefetch (A staged 1 tile ahead, B staged 2 tiles ahead), ONE counted
// vmcnt(4) per K-tile placed after the phase-4 MFMA (never drain-0 in loop).

#define SEQ 512
#define DIN 1024
#define DH  4096
#define NCAT 16
#define NB   64

#define BM 256
#define BN 256
#define BK 64
#define NT 512
#define NTILES (DIN / BK)

typedef __attribute__((ext_vector_type(8))) short   short8;
typedef __attribute__((ext_vector_type(8))) __bf16  bf16x8;
typedef __attribute__((ext_vector_type(4))) __bf16  bf16x4;
typedef __attribute__((ext_vector_type(4))) float   f32x4;

static __device__ __forceinline__ void gload_lds16(const void* g, void* l) {
    __builtin_amdgcn_global_load_lds(
        (const __attribute__((address_space(1))) void*)g,
        (__attribute__((address_space(3))) void*)l,
        16, 0, 0);
}

static __device__ __forceinline__ void bar() {
    asm volatile("" ::: "memory");
    __builtin_amdgcn_s_barrier();
    asm volatile("" ::: "memory");
}

#define MFMA_BF16(a, b, c) __builtin_amdgcn_mfma_f32_16x16x32_bf16((a), (b), (c), 0, 0, 0)

// ---------------- prepass 1: x f32 -> bf16 ----------------
__global__ __launch_bounds__(256)
void conv_x(const float* __restrict__ x, __bf16* __restrict__ xb, int n8) {
    int idx = blockIdx.x * 256 + threadIdx.x;
    const int stride = gridDim.x * 256;
    for (; idx < n8; idx += stride) {
        const f32x4 a = ((const f32x4*)x)[(size_t)idx * 2];
        const f32x4 b = ((const f32x4*)x)[(size_t)idx * 2 + 1];
        bf16x8 h;
        h[0]=(__bf16)a[0]; h[1]=(__bf16)a[1]; h[2]=(__bf16)a[2]; h[3]=(__bf16)a[3];
        h[4]=(__bf16)b[0]; h[5]=(__bf16)b[1]; h[6]=(__bf16)b[2]; h[7]=(__bf16)b[3];
        ((bf16x8*)xb)[idx] = h;
    }
}

// ------- prepass 2: W [C][K][N] f32 -> Wt [C][N][K] bf16 (LDS transpose) -------
__global__ __launch_bounds__(256)
void conv_w(const float* __restrict__ W, __bf16* __restrict__ wt) {
    __shared__ float lt[64][65];
    const int t  = threadIdx.x;
    const int nb = blockIdx.x * 64;
    const int kb = blockIdx.y * 64;
    const int c  = blockIdx.z;
    #pragma unroll
    for (int p = 0; p < 4; p++) {
        const int row = (t >> 4) + p * 16;
        const int col = (t & 15) * 4;
        const f32x4 v = *(const f32x4*)(W + ((size_t)c * DIN + kb + row) * DH + nb + col);
        lt[row][col] = v[0]; lt[row][col+1] = v[1];
        lt[row][col+2] = v[2]; lt[row][col+3] = v[3];
    }
    __syncthreads();
    #pragma unroll
    for (int p = 0; p < 2; p++) {
        const int n  = (t >> 3) + p * 32;
        const int k0 = (t & 7) * 8;
        bf16x8 h;
        #pragma unroll
        for (int j = 0; j < 8; j++) h[j] = (__bf16)lt[k0 + j][n];
        *(bf16x8*)(wt + ((size_t)c * DH + nb + n) * DIN + kb + k0) = h;
    }
}

// ------------- main GEMM: 256x256, BK=64, 8 waves, 4 phases/K-tile -------------
// Swizzle (verified R3/R4, 0 conflicts): LDS slot (row,g) holds source group
// g ^ (row&7); staged via inverse-permuted global address, read with same XOR.
//
// Pipeline invariant (2 loads per half-tile, in-order vmcnt retirement):
//   during tile t:  ph1 stages A(t+1)h0, ph2 A(t+1)h1, ph3 B(t+2)h0, ph4 B(t+2)h1
//   B-halves of buf[cur] are read ONLY in ph1 -> free for B(t+2) from ph3.
//   wait vmcnt(4) inside ph4 (after MFMA, before closing barrier): newest 4
//   loads = B(t+2); everything tile t+1 reads has landed. wait+barrier pair
//   also publishes other waves' global_load_lds results.

#define READQ(Q)                                                         \
    const short8 aq##Q##00 = rdfrag(As, (2*(Q)    )*16 + l15, 0);        \
    const short8 aq##Q##01 = rdfrag(As, (2*(Q)    )*16 + l15, 1);        \
    const short8 aq##Q##10 = rdfrag(As, (2*(Q) + 1)*16 + l15, 0);        \
    const short8 aq##Q##11 = rdfrag(As, (2*(Q) + 1)*16 + l15, 1);

#define MMAQ(Q)                                                                   \
    __builtin_amdgcn_s_setprio(1);                                                \
    _Pragma("unroll")                                                             \
    for (int fn = 0; fn < 4; fn++) {                                              \
        acc[2*(Q)][fn]     = MFMA_BF16(aq##Q##00, bq[fn][0], acc[2*(Q)][fn]);     \
        acc[2*(Q)][fn]     = MFMA_BF16(aq##Q##01, bq[fn][1], acc[2*(Q)][fn]);     \
        acc[2*(Q) + 1][fn] = MFMA_BF16(aq##Q##10, bq[fn][0], acc[2*(Q) + 1][fn]); \
        acc[2*(Q) + 1][fn] = MFMA_BF16(aq##Q##11, bq[fn][1], acc[2*(Q) + 1][fn]); \
    }                                                                             \
    __builtin_amdgcn_s_setprio(0);

__global__ __launch_bounds__(NT, 2)
void gemm_bt8(const __bf16* __restrict__ xb, const int* __restrict__ cat_ids,
              const __bf16* __restrict__ wt, const float* __restrict__ bias,
              float* __restrict__ out) {
    __shared__ __align__(16) __bf16 lA[2][2][128 * 64];   // [buf][half] 64 KB
    __shared__ __align__(16) __bf16 lB[2][2][128 * 64];   // 64 KB

    const int t    = threadIdx.x;
    const int lane = t & 63;
    const int w    = t >> 6;
    const int wm   = (w >> 2) * 128;     // 2 m-waves
    const int wn   = (w & 3) * 64;       // 4 n-waves
    const int l15  = lane & 15;
    const int lg   = lane >> 4;

    // T1: bijective XCD swizzle (gridDim.x % 8 == 0)
    const unsigned o = blockIdx.x;
    const unsigned s = (o & 7) * (gridDim.x >> 3) + (o >> 3);
    const int bb = s >> 5;
    const int nb = ((s >> 1) & 15) * BN;
    const int mb = (s & 1) * BM;
    const int c  = cat_ids[bb];

    const __bf16* xp = xb + ((size_t)bb * SEQ + mb) * DIN;
    const __bf16* wp = wt + ((size_t)c * DH + nb) * DIN;

    // staging: 2 chunks/thread/half-tile; chunk ch: row=ch>>3, grp=ch&7,
    // source grp' = grp ^ (row&7)  (inverse swizzle on the GLOBAL side)
    int srow[2], scol[2], sdst[2];
    #pragma unroll
    for (int L = 0; L < 2; L++) {
        const int ch = L * NT + t;
        srow[L] = ch >> 3;
        scol[L] = ((ch & 7) ^ ((ch >> 3) & 7)) * 8;
        sdst[L] = ch * 8;
    }
    auto stageA = [&](int buf, int half, int kt) {
        #pragma unroll
        for (int L = 0; L < 2; L++)
            gload_lds16(xp + (size_t)(half * 128 + srow[L]) * DIN + kt + scol[L],
                        &lA[buf][half][sdst[L]]);
    };
    auto stageB = [&](int buf, int half, int kt) {
        #pragma unroll
        for (int L = 0; L < 2; L++)
            gload_lds16(wp + (size_t)(half * 128 + srow[L]) * DIN + kt + scol[L],
                        &lB[buf][half][sdst[L]]);
    };
    auto rdfrag = [&](const __bf16* slot, int row, int ks) -> short8 {
        const int off = row * 128 + ((ks * 64 + lg * 16) ^ ((row & 7) << 4));
        return *(const short8*)((const char*)slot + off);
    };

    f32x4 acc[8][4];
    #pragma unroll
    for (int i = 0; i < 8; i++)
        #pragma unroll
        for (int j = 0; j < 4; j++) acc[i][j] = (f32x4)0.f;
    short8 bq[4][2];

    // prologue: tile0 (A+B) + tile1's B halves; wait tile0 landed (newest 4
    // loads = B(1)); barrier publishes cross-wave.
    stageA(0, 0, 0); stageA(0, 1, 0);
    stageB(0, 0, 0); stageB(0, 1, 0);
    stageB(1, 0, BK); stageB(1, 1, BK);
    asm volatile("s_waitcnt vmcnt(4)" ::: "memory");
    bar();

    for (int j = 0; j < NTILES; ++j) {
        const int cur = j & 1;
        const int nxt = cur ^ 1;
        const bool pfA = (j + 1 < NTILES);
        const bool pfB = (j + 2 < NTILES);
        const __bf16* As = &lA[cur][wm >> 7][0];
        const __bf16* Bs = &lB[cur][wn >> 7][0];

        // ---- phase 1: B-frags (held in regs all tile) + A quad0 ----
        #pragma unroll
        for (int fn = 0; fn < 4; fn++)
            #pragma unroll
            for (int ks = 0; ks < 2; ks++)
                bq[fn][ks] = rdfrag(Bs, (wn & 64) + fn * 16 + l15, ks);
        READQ(0)
        if (pfA) stageA(nxt, 0, (j + 1) * BK);
        bar();
        MMAQ(0)
        bar();
        // ---- phase 2 ----
        READQ(1)
        if (pfA) stageA(nxt, 1, (j + 1) * BK);
        bar();
        MMAQ(1)
        bar();
        // ---- phase 3: tile t's B reads finished in ph1 -> B region free ----
        READQ(2)
        if (pfB) stageB(cur, 0, (j + 2) * BK);
        bar();
        MMAQ(2)
        bar();
        // ---- phase 4 + the one counted wait per K-tile ----
        READQ(3)
        if (pfB) stageB(cur, 1, (j + 2) * BK);
        bar();
        MMAQ(3)
        if (pfA) {
            if (pfB) asm volatile("s_waitcnt vmcnt(4)" ::: "memory");
            else     asm volatile("s_waitcnt vmcnt(0)" ::: "memory");
        }
        bar();
    }

    // epilogue: D[row = lg*4 + r][col = l15] per 16x16 frag (verified R1/R3)
    const float* bp = bias + (size_t)c * DH;
    float*       op = out + (size_t)bb * SEQ * DH;
    #pragma unroll
    for (int fn = 0; fn < 4; fn++) {
        const int col = nb + wn + fn * 16 + l15;
        const float bv = bp[col];
        #pragma unroll
        for (int fm = 0; fm < 8; fm++) {
            const int row0 = mb + wm + fm * 16 + lg * 4;
            #pragma unroll
            for (int r = 0; r < 4; r++)
                op[(size_t)(row0 + r) * DH + col] = acc[fm][fn][r] + bv;
        }
    }
}

// ---------------- fallback (ws too small): fused 128x128 ----------------
static __device__ __forceinline__ int swz_fb(int row) {
    return ((row ^ (row >> 3)) & 7) << 4;
}
__global__ __launch_bounds__(256, 2)
void cat_lin_fb(const float* __restrict__ x, const int* __restrict__ cat_ids,
                const float* __restrict__ W, const float* __restrict__ bias,
                float* __restrict__ out) {
    __shared__ unsigned char lAf[128 * 64 * 2];
    __shared__ unsigned char lBf[128 * 64 * 2];
    const int t = threadIdx.x, lane = t & 63, wave = t >> 6;
    const int wm = (wave >> 1) * 64, wn = (wave & 1) * 64;
    const int l15 = lane & 15, lg = lane >> 4;
    const int nb = blockIdx.x * 128, mb = blockIdx.y * 128, bb = blockIdx.z;
    const int c = cat_ids[bb];
    const float* xp = x + (size_t)bb * SEQ * DIN + (size_t)mb * DIN;
    const float* wp = W + (size_t)c * DIN * DH + nb;
    f32x4 acc[4][4];
    #pragma unroll
    for (int i = 0; i < 4; i++)
        #pragma unroll
        for (int j = 0; j < 4; j++) acc[i][j] = (f32x4)0.f;
    const int aM = t >> 4, aK = (t & 15) * 4;
    const int bN = (t & 31) * 4, bK = (t >> 5) * 4;
    for (int kt = 0; kt < DIN; kt += 64) {
        #pragma unroll
        for (int i = 0; i < 8; i++) {
            const int m = aM + i * 16;
            const f32x4 v = *(const f32x4*)(xp + (size_t)m * DIN + kt + aK);
            bf16x4 h;
            h[0]=(__bf16)v[0]; h[1]=(__bf16)v[1]; h[2]=(__bf16)v[2]; h[3]=(__bf16)v[3];
            *(bf16x4*)(&lAf[m * 128 + ((aK * 2) ^ swz_fb(m))]) = h;
        }
        #pragma unroll
        for (int i = 0; i < 2; i++) {
            const int k0 = bK + i * 32;
            const float* wr = wp + (size_t)(kt + k0) * DH + bN;
            const f32x4 r0 = *(const f32x4*)(wr);
            const f32x4 r1 = *(const f32x4*)(wr + DH);
            const f32x4 r2 = *(const f32x4*)(wr + 2 * (size_t)DH);
            const f32x4 r3 = *(const f32x4*)(wr + 3 * (size_t)DH);
            #pragma unroll
            for (int jj = 0; jj < 4; jj++) {
                bf16x4 h;
                h[0]=(__bf16)r0[jj]; h[1]=(__bf16)r1[jj];
                h[2]=(__bf16)r2[jj]; h[3]=(__bf16)r3[jj];
                const int n = bN + jj;
                *(bf16x4*)(&lBf[n * 128 + ((k0 * 2) ^ swz_fb(n))]) = h;
            }
        }
        __syncthreads();
        #pragma unroll
        for (int ks = 0; ks < 2; ks++) {
            const int kb2 = ks * 64 + lg * 16;
            short8 bfv[4];
            #pragma unroll
            for (int fn = 0; fn < 4; fn++) {
                const int n = wn + fn * 16 + l15;
                bfv[fn] = *(const short8*)(&lBf[n * 128 + (kb2 ^ swz_fb(n))]);
            }
            #pragma unroll
            for (int fm = 0; fm < 4; fm++) {
                const int m = wm + fm * 16 + l15;
                const short8 af = *(const short8*)(&lAf[m * 128 + (kb2 ^ swz_fb(m))]);
                #pragma unroll
                for (int fn = 0; fn < 4; fn++)
                    acc[fm][fn] = MFMA_BF16(af, bfv[fn], acc[fm][fn]);
            }
        }
        __syncthreads();
    }
    const float* bp = bias + (size_t)c * DH;
    float* op = out + (size_t)bb * SEQ * DH;
    #pragma unroll
    for (int fn = 0; fn < 4; fn++) {
        const int col = nb + wn + fn * 16 + l15;
        const float bv = bp[col];
        #pragma unroll
        for (int fm = 0; fm < 4; fm++) {
            const int row0 = mb + wm + fm * 16 + lg * 4;
            #pragma unroll
            for (int r = 0; r < 4; r++)
                op[(size_t)(row0 + r) * DH + col] = acc[fm][fn][r] + bv;
        }
    }
}

extern "C" void kernel_launch(void* const* d_in, const int* in_sizes, int n_in,
                              void* d_out, int out_size, void* d_ws, size_t ws_size,
                              hipStream_t stream) {
    const float* x   = (const float*)d_in[0];
    const int*   cid = (const int*)d_in[1];
    const float* W   = (const float*)d_in[2];
    const float* b   = (const float*)d_in[3];
    float*       out = (float*)d_out;

    const size_t xb_bytes = (size_t)NB * SEQ * DIN * 2;
    const size_t wt_bytes = (size_t)NCAT * DH * DIN * 2;

    if (ws_size >= xb_bytes + wt_bytes) {
        __bf16* xbuf = (__bf16*)d_ws;
        __bf16* wbuf = (__bf16*)((char*)d_ws + xb_bytes);
        conv_x<<<2048, 256, 0, stream>>>(x, xbuf, NB * SEQ * DIN / 8);
        dim3 gw(DH / 64, DIN / 64, NCAT);
        conv_w<<<gw, 256, 0, stream>>>(W, wbuf);
        // 2048 blocks: 64 batches x (16 nb x 2 mb), flattened for XCD swizzle
        gemm_bt8<<<dim3(NB * (DH / BN) * (SEQ / BM)), dim3(NT), 0, stream>>>(
            xbuf, cid, wbuf, b, out);
    } else {
        dim3 gg(DH / 128, SEQ / 128, NB);
        cat_lin_fb<<<gg, 256, 0, stream>>>(x, cid, W, b, out);
    }
}

// Round 6
// 487.622 us; speedup vs baseline: 1.2168x; 1.1938x over previous
//
#include <hip/hip_runtime.h>
#include <hip/hip_bf16.h>

// out[b,s,h] = sum_d x[b,s,d] * W[cat[b],d,h] + bias[cat[b],h]
// Strategy: prepass casts x -> bf16 [B][S][K], W -> bf16 transposed [C][N][K]
// in d_ws; then the R3-proven 128x128 2-barrier MFMA GEMM (global_load_lds +
// both-sides XOR swizzle), now with a locality-ordered flattened grid:
// mb-fastest (W-panel reuse x4, x-panels L2-hot) + bijective XCD chunking.

#define SEQ 512
#define DIN 1024
#define DH  4096
#define NCAT 16
#define NB   64

typedef __attribute__((ext_vector_type(8))) short   short8;
typedef __attribute__((ext_vector_type(8))) __bf16  bf16x8;
typedef __attribute__((ext_vector_type(4))) __bf16  bf16x4;
typedef __attribute__((ext_vector_type(4))) float   f32x4;

static __device__ __forceinline__ void gload_lds16(const void* g, void* l) {
    __builtin_amdgcn_global_load_lds(
        (const __attribute__((address_space(1))) void*)g,
        (__attribute__((address_space(3))) void*)l,
        16, 0, 0);
}

#define MFMA_BF16(a, b, c) __builtin_amdgcn_mfma_f32_16x16x32_bf16((a), (b), (c), 0, 0, 0)

// ---------------- prepass 1: x f32 -> bf16 ----------------
__global__ __launch_bounds__(256)
void conv_x(const float* __restrict__ x, __bf16* __restrict__ xb, int n8) {
    int idx = blockIdx.x * 256 + threadIdx.x;
    const int stride = gridDim.x * 256;
    for (; idx < n8; idx += stride) {
        const f32x4 a = ((const f32x4*)x)[(size_t)idx * 2];
        const f32x4 b = ((const f32x4*)x)[(size_t)idx * 2 + 1];
        bf16x8 h;
        h[0]=(__bf16)a[0]; h[1]=(__bf16)a[1]; h[2]=(__bf16)a[2]; h[3]=(__bf16)a[3];
        h[4]=(__bf16)b[0]; h[5]=(__bf16)b[1]; h[6]=(__bf16)b[2]; h[7]=(__bf16)b[3];
        ((bf16x8*)xb)[idx] = h;
    }
}

// ------- prepass 2: W [C][K][N] f32 -> Wt [C][N][K] bf16 (LDS transpose) -------
__global__ __launch_bounds__(256)
void conv_w(const float* __restrict__ W, __bf16* __restrict__ wt) {
    __shared__ float lt[64][65];
    const int t  = threadIdx.x;
    const int nb = blockIdx.x * 64;
    const int kb = blockIdx.y * 64;
    const int c  = blockIdx.z;
    #pragma unroll
    for (int p = 0; p < 4; p++) {
        const int row = (t >> 4) + p * 16;
        const int col = (t & 15) * 4;
        const f32x4 v = *(const f32x4*)(W + ((size_t)c * DIN + kb + row) * DH + nb + col);
        lt[row][col] = v[0]; lt[row][col+1] = v[1];
        lt[row][col+2] = v[2]; lt[row][col+3] = v[3];
    }
    __syncthreads();
    #pragma unroll
    for (int p = 0; p < 2; p++) {
        const int n  = (t >> 3) + p * 32;
        const int k0 = (t & 7) * 8;
        bf16x8 h;
        #pragma unroll
        for (int j = 0; j < 8; j++) h[j] = (__bf16)lt[k0 + j][n];
        *(bf16x8*)(wt + ((size_t)c * DH + nb + n) * DIN + kb + k0) = h;
    }
}

// ---------------- main GEMM: R3-proven 128x128, BK=64, 4 waves ----------------
// LDS slot (row, g) holds source group g ^ (row&7) (g = 16B group, 8/row);
// staged via inverse-permuted GLOBAL address, read with same XOR.
// Verified R3: 0 bank conflicts, VGPR 64, ~3.4 blocks/CU.
__global__ __launch_bounds__(256, 2)
void gemm_bt(const __bf16* __restrict__ xb, const int* __restrict__ cat_ids,
             const __bf16* __restrict__ wt, const float* __restrict__ bias,
             float* __restrict__ out) {
    __shared__ __align__(16) __bf16 lA[128 * 64];   // 16 KB
    __shared__ __align__(16) __bf16 lB[128 * 64];   // 16 KB

    const int t    = threadIdx.x;
    const int lane = t & 63;
    const int w    = t >> 6;
    const int wm   = (w >> 1) * 64;
    const int wn   = (w & 1) * 64;
    const int l15  = lane & 15;
    const int lg   = lane >> 4;

    // Locality-ordered flattened grid + bijective XCD chunking (8192 % 8 == 0).
    // Each XCD gets 1024 consecutive s = 8 whole batches. Within a batch:
    // mb fastest (4 blocks share one W-panel), then nb sweep (x-panels stay
    // L2-hot, expert W read once per batch), then bb.
    const unsigned o = blockIdx.x;
    const unsigned s = (o & 7) * (gridDim.x >> 3) + (o >> 3);
    const int bb  = s >> 7;            // 128 blocks per batch
    const int r   = s & 127;
    const int nb  = (r >> 2) * 128;    // 32 nb values
    const int mb  = (r & 3) * 128;     // mb fastest
    const int c   = cat_ids[bb];

    const __bf16* xp = xb + ((size_t)bb * SEQ + mb) * DIN;
    const __bf16* wp = wt + ((size_t)c * DH + nb) * DIN;

    // staging: chunk q = w*4+i covers rows q*8..q*8+7; lane>>3 = row&7.
    const int srow = lane >> 3;
    const int scol = ((lane & 7) ^ (lane >> 3)) * 8;

    f32x4 acc[4][4];
    #pragma unroll
    for (int i = 0; i < 4; i++)
        #pragma unroll
        for (int j = 0; j < 4; j++) acc[i][j] = (f32x4)0.f;

    for (int kt = 0; kt < DIN; kt += 64) {
        #pragma unroll
        for (int i = 0; i < 4; i++) {
            const int q = w * 4 + i;
            const int rr = q * 8 + srow;
            gload_lds16(xp + (size_t)rr * DIN + kt + scol, &lA[q * 512]);
            gload_lds16(wp + (size_t)rr * DIN + kt + scol, &lB[q * 512]);
        }
        __syncthreads();   // drains vmcnt(0): tiles resident + visible

        #pragma unroll
        for (int ks = 0; ks < 2; ks++) {
            const int kob = (ks * 32 + lg * 8) * 2;
            short8 bfv[4];
            #pragma unroll
            for (int fn = 0; fn < 4; fn++) {
                const int n = wn + fn * 16 + l15;
                bfv[fn] = *(const short8*)((const char*)lB +
                            (n * 128 + (kob ^ ((n & 7) << 4))));
            }
            #pragma unroll
            for (int fm = 0; fm < 4; fm++) {
                const int m = wm + fm * 16 + l15;
                const short8 af = *(const short8*)((const char*)lA +
                            (m * 128 + (kob ^ ((m & 7) << 4))));
                #pragma unroll
                for (int fn = 0; fn < 4; fn++)
                    acc[fm][fn] = MFMA_BF16(af, bfv[fn], acc[fm][fn]);
            }
        }
        __syncthreads();   // reads done before next stage overwrites
    }

    const float* bp = bias + (size_t)c * DH;
    float*       op = out + (size_t)bb * SEQ * DH;
    #pragma unroll
    for (int fn = 0; fn < 4; fn++) {
        const int col = nb + wn + fn * 16 + l15;
        const float bv = bp[col];
        #pragma unroll
        for (int fm = 0; fm < 4; fm++) {
            const int row0 = mb + wm + fm * 16 + lg * 4;
            #pragma unroll
            for (int r2 = 0; r2 < 4; r2++)
                op[(size_t)(row0 + r2) * DH + col] = acc[fm][fn][r2] + bv;
        }
    }
}

// ---------------- fallback (ws too small): fused 128x128 ----------------
static __device__ __forceinline__ int swz_fb(int row) {
    return ((row ^ (row >> 3)) & 7) << 4;
}
__global__ __launch_bounds__(256, 2)
void cat_lin_fb(const float* __restrict__ x, const int* __restrict__ cat_ids,
                const float* __restrict__ W, const float* __restrict__ bias,
                float* __restrict__ out) {
    __shared__ unsigned char lAf[128 * 64 * 2];
    __shared__ unsigned char lBf[128 * 64 * 2];
    const int t = threadIdx.x, lane = t & 63, wave = t >> 6;
    const int wm = (wave >> 1) * 64, wn = (wave & 1) * 64;
    const int l15 = lane & 15, lg = lane >> 4;
    const int nb = blockIdx.x * 128, mb = blockIdx.y * 128, bb = blockIdx.z;
    const int c = cat_ids[bb];
    const float* xp = x + (size_t)bb * SEQ * DIN + (size_t)mb * DIN;
    const float* wp = W + (size_t)c * DIN * DH + nb;
    f32x4 acc[4][4];
    #pragma unroll
    for (int i = 0; i < 4; i++)
        #pragma unroll
        for (int j = 0; j < 4; j++) acc[i][j] = (f32x4)0.f;
    const int aM = t >> 4, aK = (t & 15) * 4;
    const int bN = (t & 31) * 4, bK = (t >> 5) * 4;
    for (int kt = 0; kt < DIN; kt += 64) {
        #pragma unroll
        for (int i = 0; i < 8; i++) {
            const int m = aM + i * 16;
            const f32x4 v = *(const f32x4*)(xp + (size_t)m * DIN + kt + aK);
            bf16x4 h;
            h[0]=(__bf16)v[0]; h[1]=(__bf16)v[1]; h[2]=(__bf16)v[2]; h[3]=(__bf16)v[3];
            *(bf16x4*)(&lAf[m * 128 + ((aK * 2) ^ swz_fb(m))]) = h;
        }
        #pragma unroll
        for (int i = 0; i < 2; i++) {
            const int k0 = bK + i * 32;
            const float* wr = wp + (size_t)(kt + k0) * DH + bN;
            const f32x4 r0 = *(const f32x4*)(wr);
            const f32x4 r1 = *(const f32x4*)(wr + DH);
            const f32x4 r2 = *(const f32x4*)(wr + 2 * (size_t)DH);
            const f32x4 r3 = *(const f32x4*)(wr + 3 * (size_t)DH);
            #pragma unroll
            for (int jj = 0; jj < 4; jj++) {
                bf16x4 h;
                h[0]=(__bf16)r0[jj]; h[1]=(__bf16)r1[jj];
                h[2]=(__bf16)r2[jj]; h[3]=(__bf16)r3[jj];
                const int n = bN + jj;
                *(bf16x4*)(&lBf[n * 128 + ((k0 * 2) ^ swz_fb(n))]) = h;
            }
        }
        __syncthreads();
        #pragma unroll
        for (int ks = 0; ks < 2; ks++) {
            const int kb2 = ks * 64 + lg * 16;
            short8 bfv[4];
            #pragma unroll
            for (int fn = 0; fn < 4; fn++) {
                const int n = wn + fn * 16 + l15;
                bfv[fn] = *(const short8*)(&lBf[n * 128 + (kb2 ^ swz_fb(n))]);
            }
            #pragma unroll
            for (int fm = 0; fm < 4; fm++) {
                const int m = wm + fm * 16 + l15;
                const short8 af = *(const short8*)(&lAf[m * 128 + (kb2 ^ swz_fb(m))]);
                #pragma unroll
                for (int fn = 0; fn < 4; fn++)
                    acc[fm][fn] = MFMA_BF16(af, bfv[fn], acc[fm][fn]);
            }
        }
        __syncthreads();
    }
    const float* bp = bias + (size_t)c * DH;
    float* op = out + (size_t)bb * SEQ * DH;
    #pragma unroll
    for (int fn = 0; fn < 4; fn++) {
        const int col = nb + wn + fn * 16 + l15;
        const float bv = bp[col];
        #pragma unroll
        for (int fm = 0; fm < 4; fm++) {
            const int row0 = mb + wm + fm * 16 + lg * 4;
            #pragma unroll
            for (int r = 0; r < 4; r++)
                op[(size_t)(row0 + r) * DH + col] = acc[fm][fn][r] + bv;
        }
    }
}

extern "C" void kernel_launch(void* const* d_in, const int* in_sizes, int n_in,
                              void* d_out, int out_size, void* d_ws, size_t ws_size,
                              hipStream_t stream) {
    const float* x   = (const float*)d_in[0];
    const int*   cid = (const int*)d_in[1];
    const float* W   = (const float*)d_in[2];
    const float* b   = (const float*)d_in[3];
    float*       out = (float*)d_out;

    const size_t xb_bytes = (size_t)NB * SEQ * DIN * 2;
    const size_t wt_bytes = (size_t)NCAT * DH * DIN * 2;

    if (ws_size >= xb_bytes + wt_bytes) {
        __bf16* xbuf = (__bf16*)d_ws;
        __bf16* wbuf = (__bf16*)((char*)d_ws + xb_bytes);
        conv_x<<<2048, 256, 0, stream>>>(x, xbuf, NB * SEQ * DIN / 8);
        dim3 gw(DH / 64, DIN / 64, NCAT);
        conv_w<<<gw, 256, 0, stream>>>(W, wbuf);
        // 8192 blocks flattened: bb x (nb x mb), mb fastest; XCD-chunked.
        gemm_bt<<<dim3(NB * (DH / 128) * (SEQ / 128)), dim3(256), 0, stream>>>(
            xbuf, cid, wbuf, b, out);
    } else {
        dim3 gg(DH / 128, SEQ / 128, NB);
        cat_lin_fb<<<gg, 256, 0, stream>>>(x, cid, W, b, out);
    }
}